// Round 1
// baseline (1981.661 us; speedup 1.0000x reference)
//
#include <hip/hip_runtime.h>
#include <math.h>

#define BATCH 32768
#define SEQLEN 200
#define PSTEPS 50
#define HID 32
#define IND 4

// sigmoid(x) = 1/(1+exp(-x)).  __expf -> v_exp_f32 path; inf/0 extremes fold
// to exactly 0/1 so no clamping needed.
__device__ __forceinline__ float sigmoid_(float x) {
    return 1.0f / (1.0f + __expf(-x));
}
// tanh(x) = 1 - 2/(exp(2x)+1).  x->+inf: exp=inf -> 1; x->-inf: exp=0 -> -1.
__device__ __forceinline__ float tanh_(float x) {
    return 1.0f - 2.0f / (__expf(2.0f * x) + 1.0f);
}

// One batch element per 32-lane group (2 elements per wave64). Lane j of the
// group owns hidden index j: state h[j], c[j], and the 4 gate rows
// {j, 32+j, 64+j, 96+j} of W_ih/W_hh resident in VGPRs (4*36 = 144 floats).
// h broadcast is wave-internal __shfl (width 32) -> no LDS, no barriers.
__global__ __launch_bounds__(256, 2)
void lstm_predict_kernel(const float* __restrict__ hist,
                         const float* __restrict__ W_ih,
                         const float* __restrict__ W_hh,
                         const float* __restrict__ b_ih,
                         const float* __restrict__ b_hh,
                         const float* __restrict__ W_pred,
                         const float* __restrict__ b_pred,
                         float* __restrict__ out)
{
    const int tid  = blockIdx.x * blockDim.x + threadIdx.x;
    const int elem = tid >> 5;   // batch element
    const int j    = tid & 31;   // hidden index owned by this lane

    // ---- load per-lane weights (once; reused 250 steps) ----
    float wih[4][IND];   // [gate][d]
    float whh[4][HID];   // [gate][m]  -> 128 VGPRs
    float bias[4];
    #pragma unroll
    for (int g = 0; g < 4; ++g) {
        const int row = g * HID + j;
        #pragma unroll
        for (int d = 0; d < IND; ++d) wih[g][d] = W_ih[row * IND + d];
        #pragma unroll
        for (int m = 0; m < HID; ++m) whh[g][m] = W_hh[row * HID + m];
        bias[g] = b_ih[row] + b_hh[row];
    }
    float wp[4];
    #pragma unroll
    for (int d = 0; d < 4; ++d) wp[d] = W_pred[d * HID + j];
    const float bp0 = b_pred[0], bp1 = b_pred[1], bp2 = b_pred[2], bp3 = b_pred[3];

    const float* xp = hist + (size_t)elem * SEQLEN * IND;
    float h = 0.0f, c = 0.0f;

    // ---- encode history: 200 steps ----
    float4 xv = *(const float4*)(xp);   // t = 0 (all 32 lanes load same 16B: broadcast)
    for (int t = 0; t < SEQLEN; ++t) {
        // prefetch next x one step ahead (hidden behind the 160-instr h-loop)
        const int tn = (t + 1 < SEQLEN) ? (t + 1) : (SEQLEN - 1);
        float4 xn = *(const float4*)(xp + tn * IND);

        float gi = bias[0], gf = bias[1], gg = bias[2], go = bias[3];
        #pragma unroll
        for (int m = 0; m < HID; ++m) {
            const float hm = __shfl(h, m, 32);
            gi = fmaf(whh[0][m], hm, gi);
            gf = fmaf(whh[1][m], hm, gf);
            gg = fmaf(whh[2][m], hm, gg);
            go = fmaf(whh[3][m], hm, go);
        }
        // x-part last (gives the prefetched load time to land)
        gi = fmaf(wih[0][0], xv.x, fmaf(wih[0][1], xv.y, fmaf(wih[0][2], xv.z, fmaf(wih[0][3], xv.w, gi))));
        gf = fmaf(wih[1][0], xv.x, fmaf(wih[1][1], xv.y, fmaf(wih[1][2], xv.z, fmaf(wih[1][3], xv.w, gf))));
        gg = fmaf(wih[2][0], xv.x, fmaf(wih[2][1], xv.y, fmaf(wih[2][2], xv.z, fmaf(wih[2][3], xv.w, gg))));
        go = fmaf(wih[3][0], xv.x, fmaf(wih[3][1], xv.y, fmaf(wih[3][2], xv.z, fmaf(wih[3][3], xv.w, go))));

        const float cn = sigmoid_(gf) * c + sigmoid_(gi) * tanh_(gg);
        h = sigmoid_(go) * tanh_(cn);
        c = cn;
        xv = xn;
    }

    // ---- autoregressive decode: 50 steps (c reset to 0 each step -> f-gate dead) ----
    float* op = out + (size_t)elem * PSTEPS * IND;
    for (int p = 0; p < PSTEPS; ++p) {
        // pred[d] = b_pred[d] + sum_j h_j * W_pred[d][j] ; butterfly leaves the
        // full pred vector in every lane (needed as next-step x anyway).
        float p0 = h * wp[0], p1 = h * wp[1], p2 = h * wp[2], p3 = h * wp[3];
        #pragma unroll
        for (int k = 1; k < 32; k <<= 1) {
            p0 += __shfl_xor(p0, k, 32);
            p1 += __shfl_xor(p1, k, 32);
            p2 += __shfl_xor(p2, k, 32);
            p3 += __shfl_xor(p3, k, 32);
        }
        p0 += bp0; p1 += bp1; p2 += bp2; p3 += bp3;
        if (j == 0) {
            float4 o4 = make_float4(p0, p1, p2, p3);
            *(float4*)(op + p * IND) = o4;
        }

        // cell(h, c=0, x=pred): c_new = sigmoid(i)*tanh(g); f-gate unused.
        float gi = bias[0], gg = bias[2], go = bias[3];
        #pragma unroll
        for (int m = 0; m < HID; ++m) {
            const float hm = __shfl(h, m, 32);
            gi = fmaf(whh[0][m], hm, gi);
            gg = fmaf(whh[2][m], hm, gg);
            go = fmaf(whh[3][m], hm, go);
        }
        gi = fmaf(wih[0][0], p0, fmaf(wih[0][1], p1, fmaf(wih[0][2], p2, fmaf(wih[0][3], p3, gi))));
        gg = fmaf(wih[2][0], p0, fmaf(wih[2][1], p1, fmaf(wih[2][2], p2, fmaf(wih[2][3], p3, gg))));
        go = fmaf(wih[3][0], p0, fmaf(wih[3][1], p1, fmaf(wih[3][2], p2, fmaf(wih[3][3], p3, go))));

        const float cn = sigmoid_(gi) * tanh_(gg);
        h = sigmoid_(go) * tanh_(cn);
    }
}

extern "C" void kernel_launch(void* const* d_in, const int* in_sizes, int n_in,
                              void* d_out, int out_size, void* d_ws, size_t ws_size,
                              hipStream_t stream) {
    const float* hist   = (const float*)d_in[0];
    const float* W_ih   = (const float*)d_in[1];
    const float* W_hh   = (const float*)d_in[2];
    const float* b_ih   = (const float*)d_in[3];
    const float* b_hh   = (const float*)d_in[4];
    const float* W_pred = (const float*)d_in[5];
    const float* b_pred = (const float*)d_in[6];
    float* out = (float*)d_out;

    const int threads = BATCH * 32;          // 32 lanes per batch element
    const int block   = 256;
    const int grid    = threads / block;     // 4096 blocks, exact
    lstm_predict_kernel<<<grid, block, 0, stream>>>(hist, W_ih, W_hh, b_ih, b_hh,
                                                    W_pred, b_pred, out);
}

// Round 2
// 822.903 us; speedup vs baseline: 2.4081x; 2.4081x over previous
//
#include <hip/hip_runtime.h>
#include <math.h>

#define BATCH 32768
#define SEQLEN 200
#define PSTEPS 50
#define HID 32
#define LDS_PAD 36   // 32+4: float row stride 36 -> 2-way max bank aliasing on b128 reads (free)

typedef __attribute__((ext_vector_type(8))) short short8;
typedef __attribute__((ext_vector_type(4))) float floatx4;

__device__ __forceinline__ float sigmoid_(float x) { return 1.0f / (1.0f + __expf(-x)); }
__device__ __forceinline__ float tanh_(float x) { return 1.0f - 2.0f / (__expf(2.0f * x) + 1.0f); }

// Truncation hi/lo bf16 split: hi = top 16 bits, lo = bf16_trunc(x - hi).
// Reconstruction error ~2^-16 relative -- far under the 5e-3 output threshold.
__device__ __forceinline__ void split2(float x, short& hi, short& lo) {
    unsigned u = __float_as_uint(x);
    hi = (short)(u >> 16);
    float hf = __uint_as_float(u & 0xFFFF0000u);
    float l = x - hf;                      // exact in fp32
    lo = (short)(__float_as_uint(l) >> 16);
}

// One wave = 16 batch elements. M=batch(16), N=gate tiles (8 x 16 = 128), K=hid(32).
// Per step per N-tile: 4 MFMAs:
//   acc  = mfma(A2, B2, 0)          A2 = [x_hi|x_hi|x_lo|1|1|0..], B2 = [Wih_hi;Wih_lo;Wih_hi;bias_hi;bias_lo;0..]
//   acc += mfma(Ah_hi, Bhh_hi)      h@W_hh hi/lo split (AlBl term dropped, ~2^-18)
//   acc += mfma(Ah_hi, Bhh_lo)
//   acc += mfma(Ah_lo, Bhh_hi)
// C layout: row(batch) = quad*4+reg, col(gate) = lane&15  [m89]
// A layout: m = lane&15, k = quad*8+j                     [m118-122]
// h round-trips C-layout -> LDS(fp32) -> A-layout each step; c-state stays lane-local.
__global__ __launch_bounds__(256, 2)
void lstm_mfma_kernel(const float* __restrict__ hist, const float* __restrict__ W_ih,
                      const float* __restrict__ W_hh, const float* __restrict__ b_ih,
                      const float* __restrict__ b_hh, const float* __restrict__ W_pred,
                      const float* __restrict__ b_pred, float* __restrict__ out)
{
    const int lane = threadIdx.x & 63;
    const int wv   = threadIdx.x >> 6;          // wave in block (0..3)
    const int m    = lane & 15;                 // operand M/N index
    const int quad = lane >> 4;                 // 0..3
    const int elem0 = (blockIdx.x * 4 + wv) * 16;

    __shared__ __align__(16) float h_lds_all[4][16][LDS_PAD];
    float (*hl)[LDS_PAD] = h_lds_all[wv];       // per-wave region: no __syncthreads ever

    // ---- build resident weight fragments (once; reused 250 steps) ----
    short8 Bh_hi[8], Bh_lo[8], B2[8];
    #pragma unroll
    for (int n = 0; n < 8; ++n) {
        const int gc = n * 16 + m;              // gate row 0..127
        short8 bh, bl;
        #pragma unroll
        for (int j = 0; j < 8; ++j) {
            short hi, lo; split2(W_hh[gc * HID + quad * 8 + j], hi, lo);
            bh[j] = hi; bl[j] = lo;
        }
        Bh_hi[n] = bh; Bh_lo[n] = bl;
        short8 b2 = {0,0,0,0,0,0,0,0};
        if (quad == 0) {            // K rows 0-7: Wih_hi | Wih_lo
            #pragma unroll
            for (int j = 0; j < 4; ++j) {
                short hi, lo; split2(W_ih[gc * 4 + j], hi, lo);
                b2[j] = hi; b2[4 + j] = lo;
            }
        } else if (quad == 1) {     // K rows 8-11: Wih_hi ; row12: bias_hi ; row13: bias_lo
            #pragma unroll
            for (int j = 0; j < 4; ++j) {
                short hi, lo; split2(W_ih[gc * 4 + j], hi, lo);
                b2[j] = hi;
            }
            short hi, lo; split2(b_ih[gc] + b_hh[gc], hi, lo);
            b2[4] = hi; b2[5] = lo;
        }
        B2[n] = b2;
    }
    const short one_bf = (short)0x3F80;         // bf16(1.0)

    // ---- init h = 0 in LDS, c = 0 in regs ----
    float cst[2][4];
    #pragma unroll
    for (int hf = 0; hf < 2; ++hf)
        #pragma unroll
        for (int r = 0; r < 4; ++r) { cst[hf][r] = 0.f; hl[quad * 4 + r][hf * 16 + m] = 0.f; }
    asm volatile("s_waitcnt lgkmcnt(0)" ::: "memory");

    // ---- encode: 200 steps ----
    const float4* xp = (const float4*)(hist + (size_t)(elem0 + m) * (SEQLEN * 4));
    float4 xv = xp[0];
    for (int t = 0; t < SEQLEN; ++t) {
        // h fragments from LDS (A layout: batch m = lane&15, k = quad*8+j)
        float4 h0 = *(const float4*)&hl[m][quad * 8];
        float4 h1 = *(const float4*)&hl[m][quad * 8 + 4];
        short8 ah, al;
        {
            float hv[8] = {h0.x, h0.y, h0.z, h0.w, h1.x, h1.y, h1.z, h1.w};
            #pragma unroll
            for (int j = 0; j < 8; ++j) { short hi, lo; split2(hv[j], hi, lo); ah[j] = hi; al[j] = lo; }
        }
        // A2 from x_t
        short8 a2 = {0,0,0,0,0,0,0,0};
        {
            float xvf[4] = {xv.x, xv.y, xv.z, xv.w};
            short xh[4], xl[4];
            #pragma unroll
            for (int d = 0; d < 4; ++d) split2(xvf[d], xh[d], xl[d]);
            if (quad == 0) {
                a2[0]=xh[0]; a2[1]=xh[1]; a2[2]=xh[2]; a2[3]=xh[3];
                a2[4]=xh[0]; a2[5]=xh[1]; a2[6]=xh[2]; a2[7]=xh[3];
            } else if (quad == 1) {
                a2[0]=xl[0]; a2[1]=xl[1]; a2[2]=xl[2]; a2[3]=xl[3];
                a2[4]=one_bf; a2[5]=one_bf;
            }
        }
        // prefetch next x (in flight across MFMA + cells)
        float4 xn = xp[(t + 1 < SEQLEN) ? t + 1 : t];

        floatx4 acc[8];
        #pragma unroll
        for (int n = 0; n < 8; ++n) {
            floatx4 a = {0.f, 0.f, 0.f, 0.f};
            a = __builtin_amdgcn_mfma_f32_16x16x32_bf16(a2, B2[n], a, 0, 0, 0);
            a = __builtin_amdgcn_mfma_f32_16x16x32_bf16(ah, Bh_hi[n], a, 0, 0, 0);
            a = __builtin_amdgcn_mfma_f32_16x16x32_bf16(ah, Bh_lo[n], a, 0, 0, 0);
            a = __builtin_amdgcn_mfma_f32_16x16x32_bf16(al, Bh_hi[n], a, 0, 0, 0);
            acc[n] = a;
        }
        // cells: tiles 0,1=i  2,3=f  4,5=g  6,7=o ; (row=quad*4+reg, unit = hf*16 + m)
        #pragma unroll
        for (int hf = 0; hf < 2; ++hf) {
            #pragma unroll
            for (int r = 0; r < 4; ++r) {
                float gi = acc[0 + hf][r], gf = acc[2 + hf][r];
                float gg = acc[4 + hf][r], go = acc[6 + hf][r];
                float cn = sigmoid_(gf) * cst[hf][r] + sigmoid_(gi) * tanh_(gg);
                float hn = sigmoid_(go) * tanh_(cn);
                cst[hf][r] = cn;
                hl[quad * 4 + r][hf * 16 + m] = hn;
            }
        }
        asm volatile("s_waitcnt lgkmcnt(0)" ::: "memory");  // DS in-order per wave; fence write->read
        xv = xn;
    }

    // ---- decode: 50 steps (c reset to 0 -> f-gate dead; tiles 2,3 skipped) ----
    float wp[4][8];                              // W_pred K-slice (loaded after encode: not live above)
    #pragma unroll
    for (int d = 0; d < 4; ++d)
        #pragma unroll
        for (int j = 0; j < 8; ++j) wp[d][j] = W_pred[d * HID + quad * 8 + j];
    const float bp0 = b_pred[0], bp1 = b_pred[1], bp2 = b_pred[2], bp3 = b_pred[3];
    float bp[4] = {bp0, bp1, bp2, bp3};

    float* op = out + (size_t)(elem0 + m) * (PSTEPS * 4);
    for (int p = 0; p < PSTEPS; ++p) {
        float4 h0 = *(const float4*)&hl[m][quad * 8];
        float4 h1 = *(const float4*)&hl[m][quad * 8 + 4];
        float hv[8] = {h0.x, h0.y, h0.z, h0.w, h1.x, h1.y, h1.z, h1.w};

        // pred[d] = b_pred[d] + sum_k h[m][k] * W_pred[d][k]  (fp32, quad-reduced)
        float pd[4];
        #pragma unroll
        for (int d = 0; d < 4; ++d) {
            float s = 0.f;
            #pragma unroll
            for (int j = 0; j < 8; ++j) s = fmaf(hv[j], wp[d][j], s);
            s += __shfl_xor(s, 16);
            s += __shfl_xor(s, 32);
            pd[d] = s + bp[d];
        }
        if (quad == 0) *(float4*)(op + p * 4) = make_float4(pd[0], pd[1], pd[2], pd[3]);

        if (p + 1 < PSTEPS) {
            short8 ah, al;
            #pragma unroll
            for (int j = 0; j < 8; ++j) { short hi, lo; split2(hv[j], hi, lo); ah[j] = hi; al[j] = lo; }
            short8 a2 = {0,0,0,0,0,0,0,0};
            {
                short xh[4], xl[4];
                #pragma unroll
                for (int d = 0; d < 4; ++d) split2(pd[d], xh[d], xl[d]);
                if (quad == 0) {
                    a2[0]=xh[0]; a2[1]=xh[1]; a2[2]=xh[2]; a2[3]=xh[3];
                    a2[4]=xh[0]; a2[5]=xh[1]; a2[6]=xh[2]; a2[7]=xh[3];
                } else if (quad == 1) {
                    a2[0]=xl[0]; a2[1]=xl[1]; a2[2]=xl[2]; a2[3]=xl[3];
                    a2[4]=one_bf; a2[5]=one_bf;
                }
            }
            // tiles: 0,1 = i ; 4,5 = g ; 6,7 = o  -> acc idx 0,1 / 2,3 / 4,5
            floatx4 acc[6];
            #pragma unroll
            for (int nn = 0; nn < 6; ++nn) {
                const int n = (nn < 2) ? nn : nn + 2;
                floatx4 a = {0.f, 0.f, 0.f, 0.f};
                a = __builtin_amdgcn_mfma_f32_16x16x32_bf16(a2, B2[n], a, 0, 0, 0);
                a = __builtin_amdgcn_mfma_f32_16x16x32_bf16(ah, Bh_hi[n], a, 0, 0, 0);
                a = __builtin_amdgcn_mfma_f32_16x16x32_bf16(ah, Bh_lo[n], a, 0, 0, 0);
                a = __builtin_amdgcn_mfma_f32_16x16x32_bf16(al, Bh_hi[n], a, 0, 0, 0);
                acc[nn] = a;
            }
            #pragma unroll
            for (int hf = 0; hf < 2; ++hf) {
                #pragma unroll
                for (int r = 0; r < 4; ++r) {
                    float gi = acc[0 + hf][r], gg = acc[2 + hf][r], go = acc[4 + hf][r];
                    float cn = sigmoid_(gi) * tanh_(gg);
                    float hn = sigmoid_(go) * tanh_(cn);
                    hl[quad * 4 + r][hf * 16 + m] = hn;
                }
            }
            asm volatile("s_waitcnt lgkmcnt(0)" ::: "memory");
        }
    }
}

extern "C" void kernel_launch(void* const* d_in, const int* in_sizes, int n_in,
                              void* d_out, int out_size, void* d_ws, size_t ws_size,
                              hipStream_t stream) {
    const float* hist   = (const float*)d_in[0];
    const float* W_ih   = (const float*)d_in[1];
    const float* W_hh   = (const float*)d_in[2];
    const float* b_ih   = (const float*)d_in[3];
    const float* b_hh   = (const float*)d_in[4];
    const float* W_pred = (const float*)d_in[5];
    const float* b_pred = (const float*)d_in[6];
    float* out = (float*)d_out;

    // 2048 waves (16 batch elems each) = 512 blocks of 256 threads; 2 blocks/CU.
    const int blocks = (BATCH / 16) / 4;
    lstm_mfma_kernel<<<blocks, 256, 0, stream>>>(hist, W_ih, W_hh, b_ih, b_hh,
                                                 W_pred, b_pred, out);
}

// Round 4
// 429.269 us; speedup vs baseline: 4.6164x; 1.9170x over previous
//
#include <hip/hip_runtime.h>
#include <math.h>

#define BATCH 32768
#define SEQLEN 200
#define PSTEPS 50
#define HID 32
#define LDS_PAD 36   // float row stride 36 -> only 2-way bank aliasing (free, m136)

typedef __attribute__((ext_vector_type(2))) _Float16 half2v;
typedef __attribute__((ext_vector_type(8))) _Float16 half8v;
typedef __attribute__((ext_vector_type(2))) __fp16   fp16x2;   // cvt_pkrtz return type
typedef __attribute__((ext_vector_type(4))) float floatx4;

#define EXP2 __builtin_amdgcn_exp2f      // v_exp_f32: 2^x
#define RCPF __builtin_amdgcn_rcpf       // v_rcp_f32
#define PKRTZ __builtin_amdgcn_cvt_pkrtz // v_cvt_pkrtz_f16_f32: 2xf32 -> 2xf16, 1 instr

#define L1C 1.4426950408889634f          // log2(e)
#define L2C 2.8853900817779268f          // 2*log2(e)

union H8 { unsigned int u[4]; half8v h; half2v h2[4]; };
union HU { fp16x2 h; unsigned int u; };

__device__ __forceinline__ unsigned int pk(float a, float b) {
    HU t; t.h = PKRTZ(a, b); return t.u;
}

// One wave = 16 batch elements. Per step, gates[16b x 128g] via f16 MFMA:
//   per 16-gate tile n: acc = mfma(ah, Bh[n], mfma(a2, B2[n], 0))
//   a2 (quad0 only): [x_f16(4) | 1 | 1 | 0 | 0]
//   B2 (quad0 only): rows0-3 = W_ih, row4 = bias_hi_f16, row5 = bias_lo_f16
// f16 single-term: W RNE (2^-12), h RTZ (2^-11) -> gate err ~1e-4 << 5e-3 thr.
// C layout: row(batch)=quad*4+reg, col(gate)=lane&15; A: m=lane&15, k=quad*8+j.
__global__ __launch_bounds__(256, 2)
void lstm_mfma_kernel(const float* __restrict__ hist, const float* __restrict__ W_ih,
                      const float* __restrict__ W_hh, const float* __restrict__ b_ih,
                      const float* __restrict__ b_hh, const float* __restrict__ W_pred,
                      const float* __restrict__ b_pred, float* __restrict__ out)
{
    const int lane = threadIdx.x & 63;
    const int wv   = threadIdx.x >> 6;
    const int m    = lane & 15;
    const int quad = lane >> 4;
    const int elem0 = (blockIdx.x * 4 + wv) * 16;

    __shared__ __align__(16) float h_lds_all[4][16][LDS_PAD];
    float (*hl)[LDS_PAD] = h_lds_all[wv];    // per-wave region: no __syncthreads ever

    // ---- resident weight fragments (f16, built once, reused 250 steps) ----
    half8v Bh[8], B2[8];
    #pragma unroll
    for (int n = 0; n < 8; ++n) {
        const int gc = n * 16 + m;           // gate row 0..127
        H8 bh;
        #pragma unroll
        for (int jj = 0; jj < 4; ++jj) {
            bh.h2[jj] = (half2v){ (_Float16)W_hh[gc * HID + quad * 8 + 2 * jj],
                                  (_Float16)W_hh[gc * HID + quad * 8 + 2 * jj + 1] };
        }
        Bh[n] = bh.h;
        H8 b2; b2.u[0] = b2.u[1] = b2.u[2] = b2.u[3] = 0u;
        if (quad == 0) {
            b2.h2[0] = (half2v){ (_Float16)W_ih[gc * 4 + 0], (_Float16)W_ih[gc * 4 + 1] };
            b2.h2[1] = (half2v){ (_Float16)W_ih[gc * 4 + 2], (_Float16)W_ih[gc * 4 + 3] };
            float bsum = b_ih[gc] + b_hh[gc];
            _Float16 bhi = (_Float16)bsum;
            _Float16 blo = (_Float16)(bsum - (float)bhi);   // bias exact to ~2^-24
            b2.h2[2] = (half2v){ bhi, blo };                // K rows 4,5  (A = 1,1)
        }
        B2[n] = b2.h;
    }
    const unsigned int one2 = 0x3C003C00u;   // (1.0h, 1.0h)

    // ---- init h = 0 (LDS), c = 0 (regs) ----
    float cst[2][4];
    #pragma unroll
    for (int hf = 0; hf < 2; ++hf)
        #pragma unroll
        for (int r = 0; r < 4; ++r) { cst[hf][r] = 0.f; hl[quad * 4 + r][hf * 16 + m] = 0.f; }
    asm volatile("s_waitcnt lgkmcnt(0)" ::: "memory");

    // ---- encode: 200 steps ----
    const float4* xp = (const float4*)(hist + (size_t)(elem0 + m) * (SEQLEN * 4));
    float4 xv = xp[0];
    #pragma unroll 1
    for (int t = 0; t < SEQLEN; ++t) {
        float4 h0 = *(const float4*)&hl[m][quad * 8];
        float4 h1 = *(const float4*)&hl[m][quad * 8 + 4];
        H8 ahu;
        ahu.u[0] = pk(h0.x, h0.y); ahu.u[1] = pk(h0.z, h0.w);
        ahu.u[2] = pk(h1.x, h1.y); ahu.u[3] = pk(h1.z, h1.w);
        const half8v ah = ahu.h;

        const unsigned int tx0 = pk(xv.x, xv.y), tx1 = pk(xv.z, xv.w);
        H8 a2u;
        a2u.u[0] = (quad == 0) ? tx0 : 0u;
        a2u.u[1] = (quad == 0) ? tx1 : 0u;
        a2u.u[2] = (quad == 0) ? one2 : 0u;
        a2u.u[3] = 0u;
        const half8v a2 = a2u.h;

        const int tn = (t + 1 < SEQLEN) ? t + 1 : SEQLEN - 1;
        float4 xn = xp[tn];                  // in flight across MFMA + cells

        floatx4 acc[8];
        #pragma unroll
        for (int n = 0; n < 8; ++n) {
            floatx4 a = __builtin_amdgcn_mfma_f32_16x16x32_f16(a2, B2[n], (floatx4){0.f,0.f,0.f,0.f}, 0, 0, 0);
            acc[n] = __builtin_amdgcn_mfma_f32_16x16x32_f16(ah, Bh[n], a, 0, 0, 0);
        }
        // tiles 0,1=i  2,3=f  4,5=g  6,7=o (PyTorch order); unit = hf*16+m, batch = quad*4+r
        #pragma unroll
        for (int hf = 0; hf < 2; ++hf) {
            #pragma unroll
            for (int r = 0; r < 4; ++r) {
                const float gi = acc[0 + hf][r], gf = acc[2 + hf][r];
                const float gg = acc[4 + hf][r], go = acc[6 + hf][r];
                const float ei = EXP2(gi * -L1C);
                const float ef = EXP2(gf * -L1C);
                const float eo = EXP2(go * -L1C);
                const float eg = EXP2(gg * L2C);
                // sigmoid(i)*tanh(g) with one shared rcp
                const float st = (eg - 1.0f) * RCPF((1.0f + ei) * (1.0f + eg));
                float cn = fmaf(RCPF(1.0f + ef), cst[hf][r], st);
                cn = fminf(fmaxf(cn, -30.0f), 30.0f);   // fused tanh NaNs at exp overflow
                const float ec = EXP2(cn * L2C);
                const float hn = (ec - 1.0f) * RCPF((1.0f + eo) * (1.0f + ec));
                cst[hf][r] = cn;
                hl[quad * 4 + r][hf * 16 + m] = hn;
            }
        }
        asm volatile("s_waitcnt lgkmcnt(0)" ::: "memory");  // DS in-order per wave
        xv = xn;
    }

    // ---- decode: 50 steps (c reset to 0 -> f-gate dead; tiles 2,3 skipped) ----
    float wp[4][8];
    #pragma unroll
    for (int d = 0; d < 4; ++d)
        #pragma unroll
        for (int j = 0; j < 8; ++j) wp[d][j] = W_pred[d * HID + quad * 8 + j];
    float bp[4] = { b_pred[0], b_pred[1], b_pred[2], b_pred[3] };

    float* op = out + (size_t)(elem0 + m) * (PSTEPS * 4);
    #pragma unroll 1
    for (int p = 0; p < PSTEPS; ++p) {
        float4 h0 = *(const float4*)&hl[m][quad * 8];
        float4 h1 = *(const float4*)&hl[m][quad * 8 + 4];
        const float hv[8] = { h0.x, h0.y, h0.z, h0.w, h1.x, h1.y, h1.z, h1.w };

        float pd[4];
        #pragma unroll
        for (int d = 0; d < 4; ++d) {
            float s = 0.f;
            #pragma unroll
            for (int j = 0; j < 8; ++j) s = fmaf(hv[j], wp[d][j], s);
            s += __shfl_xor(s, 16);
            s += __shfl_xor(s, 32);
            pd[d] = s + bp[d];
        }
        if (quad == 0) *(float4*)(op + p * 4) = make_float4(pd[0], pd[1], pd[2], pd[3]);

        if (p + 1 < PSTEPS) {
            H8 ahu;
            ahu.u[0] = pk(hv[0], hv[1]); ahu.u[1] = pk(hv[2], hv[3]);
            ahu.u[2] = pk(hv[4], hv[5]); ahu.u[3] = pk(hv[6], hv[7]);
            const half8v ah = ahu.h;
            const unsigned int tx0 = pk(pd[0], pd[1]), tx1 = pk(pd[2], pd[3]);
            H8 a2u;
            a2u.u[0] = (quad == 0) ? tx0 : 0u;
            a2u.u[1] = (quad == 0) ? tx1 : 0u;
            a2u.u[2] = (quad == 0) ? one2 : 0u;
            a2u.u[3] = 0u;
            const half8v a2 = a2u.h;

            floatx4 acc[6];   // tiles 0,1 = i ; 4,5 = g ; 6,7 = o
            #pragma unroll
            for (int nn = 0; nn < 6; ++nn) {
                const int n = (nn < 2) ? nn : nn + 2;
                floatx4 a = __builtin_amdgcn_mfma_f32_16x16x32_f16(a2, B2[n], (floatx4){0.f,0.f,0.f,0.f}, 0, 0, 0);
                acc[nn] = __builtin_amdgcn_mfma_f32_16x16x32_f16(ah, Bh[n], a, 0, 0, 0);
            }
            #pragma unroll
            for (int hf = 0; hf < 2; ++hf) {
                #pragma unroll
                for (int r = 0; r < 4; ++r) {
                    const float gi = acc[0 + hf][r], gg = acc[2 + hf][r], go = acc[4 + hf][r];
                    const float ei = EXP2(gi * -L1C);
                    const float eo = EXP2(go * -L1C);
                    const float eg = EXP2(gg * L2C);
                    const float cn = (eg - 1.0f) * RCPF((1.0f + ei) * (1.0f + eg)); // |cn|<1
                    const float ec = EXP2(cn * L2C);
                    const float hn = (ec - 1.0f) * RCPF((1.0f + eo) * (1.0f + ec));
                    hl[quad * 4 + r][hf * 16 + m] = hn;
                }
            }
            asm volatile("s_waitcnt lgkmcnt(0)" ::: "memory");
        }
    }
}

extern "C" void kernel_launch(void* const* d_in, const int* in_sizes, int n_in,
                              void* d_out, int out_size, void* d_ws, size_t ws_size,
                              hipStream_t stream) {
    const float* hist   = (const float*)d_in[0];
    const float* W_ih   = (const float*)d_in[1];
    const float* W_hh   = (const float*)d_in[2];
    const float* b_ih   = (const float*)d_in[3];
    const float* b_hh   = (const float*)d_in[4];
    const float* W_pred = (const float*)d_in[5];
    const float* b_pred = (const float*)d_in[6];
    float* out = (float*)d_out;

    const int blocks = (BATCH / 16) / 4;   // 512 blocks = 2048 waves, 2 blocks/CU
    lstm_mfma_kernel<<<blocks, 256, 0, stream>>>(hist, W_ih, W_hh, b_ih, b_hh,
                                                 W_pred, b_pred, out);
}